// Round 1
// baseline (1602.033 us; speedup 1.0000x reference)
//
#include <hip/hip_runtime.h>

typedef short bf16x8 __attribute__((ext_vector_type(8)));
typedef float f32x4 __attribute__((ext_vector_type(4)));
typedef unsigned short u16;
typedef u16 ushort8v __attribute__((ext_vector_type(8)));

// ---- constants ----
#define VOCAB 100000
#define EMB 300
#define SEQ 40
#define BATCH 8192
#define COUT 210
#define NBLK 5
#define KPOOL 38
#define DH 35
#define NCLS 35
#define PADROWS 42          // 1 zero row + 40 seq + 1 zero row
#define PCOL 320            // padded emb row (3*320 = 960 = 30*32)
#define KDIM 960
#define NUSE 192            // only channels 0..189 feed the pool; compute 12 n-tiles
#define BM 128
#define KSTEPS 30

__device__ __forceinline__ u16 f2bf(float f) {
  unsigned u = __float_as_uint(f);
  unsigned r = 0x7FFFu + ((u >> 16) & 1u);
  return (u16)((u + r) >> 16);
}

__device__ __forceinline__ void gload_lds16(void* lds, const void* g) {
  __builtin_amdgcn_global_load_lds(
      (const __attribute__((address_space(1))) void*)g,
      (__attribute__((address_space(3))) void*)lds, 16, 0, 0);
}

// ---- kernel 1: embedding gather -> padded bf16 [BATCH][42][320] ----
__global__ __launch_bounds__(256) void k_gather(const int* __restrict__ x,
                                                const float* __restrict__ w2v,
                                                u16* __restrict__ embp) {
  int g = blockIdx.x * 256 + threadIdx.x;      // 8192*42*40 chunks of 8 bf16
  int r = g / 40, ck = g - r * 40;
  int b = r / PADROWS, sp = r - b * PADROWS;
  float v[8] = {0.f, 0.f, 0.f, 0.f, 0.f, 0.f, 0.f, 0.f};
  if (sp >= 1 && sp <= SEQ && ck <= 37) {
    int idx = x[b * SEQ + sp - 1];
    const float* src = w2v + (size_t)idx * EMB + ck * 8;
    float4 f0 = *(const float4*)src;           // w2v rows are 1200B -> 16B aligned
    v[0] = f0.x; v[1] = f0.y; v[2] = f0.z; v[3] = f0.w;
    if (ck < 37) {
      float4 f1 = *(const float4*)(src + 4);
      v[4] = f1.x; v[5] = f1.y; v[6] = f1.z; v[7] = f1.w;
    }
  }
  ushort8v o;
#pragma unroll
  for (int j = 0; j < 8; ++j) o[j] = f2bf(v[j]);
  *(ushort8v*)(embp + (size_t)g * 8) = o;
}

// ---- kernel 2: conv_w [3][300][210] -> Bt bf16 [192 cols][960 k] (zero padded) ----
__global__ __launch_bounds__(256) void k_prepB(const float* __restrict__ convw,
                                               u16* __restrict__ Bt) {
  int id = blockIdx.x * 256 + threadIdx.x;     // 192*960 = 184320
  if (id >= NUSE * KDIM) return;
  int col = id / KDIM, k = id - col * KDIM;
  int kh = k / PCOL, e = k - kh * PCOL;
  float v = (e < EMB) ? convw[(kh * EMB + e) * COUT + col] : 0.f;
  Bt[id] = f2bf(v);
}

// ---- kernel 3: conv GEMM (M=327680, N=192, K=960) + bias + relu + channel-group max ----
// 512 threads = 8 waves as 2(M) x 4(N); wave tile 64x48 (4x3 frags of 16x16).
// LDS: A [4 gran][128 row]x16B (8KB), B [4 gran][192 col]x16B (12KB); epilogue aliases as act[32][194].
__global__ __launch_bounds__(512) void k_conv_gemm(const u16* __restrict__ embp,
                                                   const u16* __restrict__ Bt,
                                                   const float* __restrict__ convb,
                                                   float* __restrict__ maxc) {
  __shared__ __align__(16) char smem[24832];
  char* smA = smem;            // 8192 B
  char* smB = smem + 8192;     // 12288 B
  float* act = (float*)smem;   // [32][194] f32 (epilogue reuse)

  const int tid = threadIdx.x;
  const int lane = tid & 63;
  const int w = tid >> 6;
  const int wr = w >> 2, wc = w & 3;
  const int l15 = lane & 15, l4 = lane >> 4;
  const int m0 = blockIdx.x * BM;

  // A staging: thread -> (granule aq = tid>>7, row ar = tid&127), LDS linear at tid*16
  const int ar = tid & 127, aq = tid >> 7;
  const int am = m0 + ar;
  const int ab = am / SEQ, as_ = am - ab * SEQ;
  const u16* gA = embp + (size_t)(ab * PADROWS + as_) * PCOL + aq * 8;
  char* ldsA = smA + tid * 16;
  // B staging: chunk c -> (q = c/192, col = c%192), LDS linear at c*16; 768 chunks
  const int q1 = tid / NUSE, col1 = tid - q1 * NUSE;
  const u16* gB1 = Bt + col1 * KDIM + q1 * 8;
  char* ldsB1 = smB + tid * 16;
  const int c2 = tid + 512;
  const int q2 = c2 / NUSE, col2 = c2 - q2 * NUSE;
  const u16* gB2 = Bt + col2 * KDIM + q2 * 8;
  char* ldsB2 = smB + c2 * 16;

  f32x4 acc[4][3];
  const f32x4 zero = {0.f, 0.f, 0.f, 0.f};
#pragma unroll
  for (int i = 0; i < 4; ++i)
#pragma unroll
    for (int j = 0; j < 3; ++j) acc[i][j] = zero;

  const int aoff = (l4 * 128 + wr * 64 + l15) * 16;   // + fm*256
  const int boff = (l4 * 192 + wc * 48 + l15) * 16;   // + fn*256

  for (int kt = 0; kt < KSTEPS; ++kt) {
    const int kofs = kt * 32;
    gload_lds16(ldsA, gA + kofs);
    gload_lds16(ldsB1, gB1 + kofs);
    if (tid < 256) gload_lds16(ldsB2, gB2 + kofs);
    __syncthreads();
    bf16x8 a[4], bfr[3];
#pragma unroll
    for (int fm = 0; fm < 4; ++fm) a[fm] = *(const bf16x8*)(smA + aoff + fm * 256);
#pragma unroll
    for (int fn = 0; fn < 3; ++fn) bfr[fn] = *(const bf16x8*)(smB + boff + fn * 256);
#pragma unroll
    for (int fm = 0; fm < 4; ++fm)
#pragma unroll
      for (int fn = 0; fn < 3; ++fn)
        acc[fm][fn] = __builtin_amdgcn_mfma_f32_16x16x32_bf16(a[fm], bfr[fn], acc[fm][fn], 0, 0, 0);
    __syncthreads();
  }

  // epilogue: 4 chunks of 32 rows; bias+relu -> LDS -> per-(row,group) max over 38 channels
#pragma unroll 1
  for (int ch = 0; ch < 4; ++ch) {
    if (wr == (ch >> 1)) {
      const int fbase = (ch & 1) * 2;
#pragma unroll
      for (int fi = 0; fi < 2; ++fi) {
#pragma unroll
        for (int fn = 0; fn < 3; ++fn) {
          const int col = wc * 48 + fn * 16 + l15;   // < 192 < 210
          const float bias = convb[col];
#pragma unroll
          for (int rg = 0; rg < 4; ++rg) {
            const int rloc = fi * 16 + l4 * 4 + rg;  // 0..31 within chunk
            float vv = acc[fbase + fi][fn][rg] + bias;
            act[rloc * 194 + col] = fmaxf(vv, 0.f);
          }
        }
      }
    }
    __syncthreads();
    if (tid < 160) {                                  // 32 rows x 5 groups
      const int rl = tid / 5, gq = tid - rl * 5;
      const float* ap = act + rl * 194 + gq * KPOOL;
      float mx = 0.f;                                 // relu => values >= 0
#pragma unroll
      for (int i = 0; i < KPOOL; ++i) mx = fmaxf(mx, ap[i]);
      const int m = m0 + ch * 32 + rl;
      const int bb = m / SEQ, ss = m - bb * SEQ;
      maxc[(bb * NBLK + gq) * SEQ + ss] = mx;         // unmasked max; mask applied in k_dense
    }
    __syncthreads();
  }
}

// ---- kernel 4: region-masked dense (120->35) + out (35->35) ----
__global__ __launch_bounds__(256) void k_dense(const float* __restrict__ maxc,
                                               const int* __restrict__ pos,
                                               const float* __restrict__ dw,
                                               const float* __restrict__ db,
                                               const float* __restrict__ ow,
                                               const float* __restrict__ ob,
                                               float* __restrict__ out) {
  __shared__ float dwL[120 * 36];
  __shared__ float owL[35 * 36];
  __shared__ float hL[64 * 36];
  __shared__ float mxL[64 * 40];
  const int tid = threadIdx.x;
  const int r0 = blockIdx.x * 64;                    // 640 blocks x 64 rows
  for (int i = tid; i < 120 * 35; i += 256) { int j = i / 35, d = i - j * 35; dwL[j * 36 + d] = dw[i]; }
  for (int i = tid; i < 35 * 35; i += 256)  { int j = i / 35, d = i - j * 35; owL[j * 36 + d] = ow[i]; }
  for (int i = tid; i < 64 * 40; i += 256)  mxL[i] = maxc[(size_t)r0 * 40 + i];
  __syncthreads();
  for (int t = tid; t < 64 * 35; t += 256) {
    const int row = t / 35, d = t - row * 35;
    const int rg = r0 + row;
    const int b = rg / NBLK;
    const int p0 = pos[b * 2], p1 = pos[b * 2 + 1];
    int e1 = min(p0, p1), e2 = max(p0, p1);
    if (e1 == 0) { e1 = 1; e2 += 1; }
    float a = db[d];
#pragma unroll
    for (int s = 0; s < SEQ; ++s) {
      const int k = (s >= e1) + (s >= e2);           // region of position s
      a += mxL[row * 40 + s] * dwL[(k * SEQ + s) * 36 + d];
    }
    hL[row * 36 + d] = a;
  }
  __syncthreads();
  for (int t = tid; t < 64 * 35; t += 256) {
    const int row = t / 35, c = t - row * 35;
    float a = ob[c];
#pragma unroll
    for (int d = 0; d < DH; ++d) a += hL[row * 36 + d] * owL[d * 36 + c];
    out[(size_t)(r0 + row) * NCLS + c] = a;
  }
}

extern "C" void kernel_launch(void* const* d_in, const int* in_sizes, int n_in,
                              void* d_out, int out_size, void* d_ws, size_t ws_size,
                              hipStream_t stream) {
  const int*   x     = (const int*)d_in[0];
  const int*   pos   = (const int*)d_in[1];
  const float* w2v   = (const float*)d_in[2];
  const float* convw = (const float*)d_in[3];
  const float* convb = (const float*)d_in[4];
  const float* dw    = (const float*)d_in[5];
  const float* db    = (const float*)d_in[6];
  const float* ow    = (const float*)d_in[7];
  const float* ob    = (const float*)d_in[8];
  float* out = (float*)d_out;

  char* ws = (char*)d_ws;
  u16* embp = (u16*)ws;                                   // 8192*42*320*2 = 220,200,960 B
  u16* Bt   = (u16*)(ws + 220200960);                     // 192*960*2    =     368,640 B
  float* maxc = (float*)(ws + 220200960 + 368640);        // 40960*40*4   =   6,553,600 B

  k_gather<<<53760, 256, 0, stream>>>(x, w2v, embp);      // 8192*42*40/256
  k_prepB<<<720, 256, 0, stream>>>(convw, Bt);            // 192*960/256
  k_conv_gemm<<<2560, 512, 0, stream>>>(embp, Bt, convb, maxc);  // 327680/128
  k_dense<<<640, 256, 0, stream>>>(maxc, pos, dw, db, ow, ob, out);
}

// Round 2
// 392.359 us; speedup vs baseline: 4.0831x; 4.0831x over previous
//
#include <hip/hip_runtime.h>

typedef short bf16x8 __attribute__((ext_vector_type(8)));
typedef float f32x4 __attribute__((ext_vector_type(4)));
typedef unsigned short u16;
typedef u16 ushort8v __attribute__((ext_vector_type(8)));

// ---- constants ----
#define VOCAB 100000
#define EMB 300
#define SEQ 40
#define BATCH 8192
#define COUT 210
#define NBLK 5
#define KPOOL 38
#define DH 35
#define NCLS 35
#define PADROWS 42          // 1 zero row + 40 seq + 1 zero row
#define PCOL 320            // padded emb row (3*320 = 960 = 30*32)
#define KDIM 960
#define NUSE 192            // only channels 0..189 feed the pool; compute 12 n-tiles
#define BM 128
#define KSTEPS 30

__device__ __forceinline__ u16 f2bf(float f) {
  unsigned u = __float_as_uint(f);
  unsigned r = 0x7FFFu + ((u >> 16) & 1u);
  return (u16)((u + r) >> 16);
}

__device__ __forceinline__ void gload_lds16(void* lds, const void* g) {
  __builtin_amdgcn_global_load_lds(
      (const __attribute__((address_space(1))) void*)g,
      (__attribute__((address_space(3))) void*)lds, 16, 0, 0);
}

// ---- kernel 1: embedding gather -> padded bf16 [BATCH][42][320] ----
__global__ __launch_bounds__(256) void k_gather(const int* __restrict__ x,
                                                const float* __restrict__ w2v,
                                                u16* __restrict__ embp) {
  int g = blockIdx.x * 256 + threadIdx.x;      // 8192*42*40 chunks of 8 bf16
  int r = g / 40, ck = g - r * 40;
  int b = r / PADROWS, sp = r - b * PADROWS;
  float v[8] = {0.f, 0.f, 0.f, 0.f, 0.f, 0.f, 0.f, 0.f};
  if (sp >= 1 && sp <= SEQ && ck <= 37) {
    int idx = x[b * SEQ + sp - 1];
    const float* src = w2v + (size_t)idx * EMB + ck * 8;
    float4 f0 = *(const float4*)src;           // w2v rows are 1200B -> 16B aligned
    v[0] = f0.x; v[1] = f0.y; v[2] = f0.z; v[3] = f0.w;
    if (ck < 37) {
      float4 f1 = *(const float4*)(src + 4);
      v[4] = f1.x; v[5] = f1.y; v[6] = f1.z; v[7] = f1.w;
    }
  }
  ushort8v o;
#pragma unroll
  for (int j = 0; j < 8; ++j) o[j] = f2bf(v[j]);
  *(ushort8v*)(embp + (size_t)g * 8) = o;
}

// ---- kernel 2: conv_w [3][300][210] -> Bt bf16 [192 cols][960 k] (zero padded) ----
__global__ __launch_bounds__(256) void k_prepB(const float* __restrict__ convw,
                                               u16* __restrict__ Bt) {
  int id = blockIdx.x * 256 + threadIdx.x;     // 192*960 = 184320
  if (id >= NUSE * KDIM) return;
  int col = id / KDIM, k = id - col * KDIM;
  int kh = k / PCOL, e = k - kh * PCOL;
  float v = (e < EMB) ? convw[(kh * EMB + e) * COUT + col] : 0.f;
  Bt[id] = f2bf(v);
}

// ---- kernel 3: conv GEMM (M=327680, N=192, K=960) + bias + relu + channel-group max ----
// 512 threads = 8 waves as 2(M) x 4(N); wave tile 64x48 (4x3 frags of 16x16).
// LDS: A [4 gran][128 row]x16B (8KB), B [4 gran][192 col]x16B (12KB); epilogue aliases as act[32][194].
__global__ __launch_bounds__(512) void k_conv_gemm(const u16* __restrict__ embp,
                                                   const u16* __restrict__ Bt,
                                                   const float* __restrict__ convb,
                                                   float* __restrict__ maxc) {
  __shared__ __align__(16) char smem[24832];
  char* smA = smem;            // 8192 B
  char* smB = smem + 8192;     // 12288 B
  float* act = (float*)smem;   // [32][194] f32 (epilogue reuse)

  const int tid = threadIdx.x;
  const int lane = tid & 63;
  const int w = tid >> 6;
  const int wr = w >> 2, wc = w & 3;
  const int l15 = lane & 15, l4 = lane >> 4;
  const int m0 = blockIdx.x * BM;

  // A staging: thread -> (granule aq = tid>>7, row ar = tid&127), LDS linear at tid*16
  const int ar = tid & 127, aq = tid >> 7;
  const int am = m0 + ar;
  const int ab = am / SEQ, as_ = am - ab * SEQ;
  const u16* gA = embp + (size_t)(ab * PADROWS + as_) * PCOL + aq * 8;
  char* ldsA = smA + tid * 16;
  // B staging: chunk c -> (q = c/192, col = c%192), LDS linear at c*16; 768 chunks
  const int q1 = tid / NUSE, col1 = tid - q1 * NUSE;
  const u16* gB1 = Bt + col1 * KDIM + q1 * 8;
  char* ldsB1 = smB + tid * 16;
  const int c2 = tid + 512;
  const int q2 = c2 / NUSE, col2 = c2 - q2 * NUSE;
  const u16* gB2 = Bt + col2 * KDIM + q2 * 8;
  char* ldsB2 = smB + c2 * 16;

  f32x4 acc[4][3];
  const f32x4 zero = {0.f, 0.f, 0.f, 0.f};
#pragma unroll
  for (int i = 0; i < 4; ++i)
#pragma unroll
    for (int j = 0; j < 3; ++j) acc[i][j] = zero;

  const int aoff = (l4 * 128 + wr * 64 + l15) * 16;   // + fm*256
  const int boff = (l4 * 192 + wc * 48 + l15) * 16;   // + fn*256

  for (int kt = 0; kt < KSTEPS; ++kt) {
    const int kofs = kt * 32;
    gload_lds16(ldsA, gA + kofs);
    gload_lds16(ldsB1, gB1 + kofs);
    if (tid < 256) gload_lds16(ldsB2, gB2 + kofs);
    __syncthreads();
    bf16x8 a[4], bfr[3];
#pragma unroll
    for (int fm = 0; fm < 4; ++fm) a[fm] = *(const bf16x8*)(smA + aoff + fm * 256);
#pragma unroll
    for (int fn = 0; fn < 3; ++fn) bfr[fn] = *(const bf16x8*)(smB + boff + fn * 256);
#pragma unroll
    for (int fm = 0; fm < 4; ++fm)
#pragma unroll
      for (int fn = 0; fn < 3; ++fn)
        acc[fm][fn] = __builtin_amdgcn_mfma_f32_16x16x32_bf16(a[fm], bfr[fn], acc[fm][fn], 0, 0, 0);
    __syncthreads();
  }

  // epilogue: 4 chunks of 32 rows; bias+relu -> LDS -> per-(row,group) max over 38 channels.
  // FULLY UNROLLED so every acc[] index is compile-time constant (rule #20: runtime
  // indexing into ext_vector arrays demotes acc to scratch -> 7.5 GB of spill traffic).
#pragma unroll
  for (int ch = 0; ch < 4; ++ch) {
    if (wr == (ch >> 1)) {
      const int fbase = (ch & 1) * 2;
#pragma unroll
      for (int fi = 0; fi < 2; ++fi) {
#pragma unroll
        for (int fn = 0; fn < 3; ++fn) {
          const int col = wc * 48 + fn * 16 + l15;   // < 192 < 210
          const float bias = convb[col];
#pragma unroll
          for (int rg = 0; rg < 4; ++rg) {
            const int rloc = fi * 16 + l4 * 4 + rg;  // 0..31 within chunk
            float vv = acc[fbase + fi][fn][rg] + bias;
            act[rloc * 194 + col] = fmaxf(vv, 0.f);
          }
        }
      }
    }
    __syncthreads();
    if (tid < 160) {                                  // 32 rows x 5 groups
      const int rl = tid / 5, gq = tid - rl * 5;
      const float* ap = act + rl * 194 + gq * KPOOL;
      float mx = 0.f;                                 // relu => values >= 0
#pragma unroll
      for (int i = 0; i < KPOOL; ++i) mx = fmaxf(mx, ap[i]);
      const int m = m0 + ch * 32 + rl;
      const int bb = m / SEQ, ss = m - bb * SEQ;
      maxc[(bb * NBLK + gq) * SEQ + ss] = mx;         // unmasked max; mask applied in k_dense
    }
    __syncthreads();
  }
}

// ---- kernel 4: region-masked dense (120->35) + out (35->35) ----
__global__ __launch_bounds__(256) void k_dense(const float* __restrict__ maxc,
                                               const int* __restrict__ pos,
                                               const float* __restrict__ dw,
                                               const float* __restrict__ db,
                                               const float* __restrict__ ow,
                                               const float* __restrict__ ob,
                                               float* __restrict__ out) {
  __shared__ float dwL[120 * 36];
  __shared__ float owL[35 * 36];
  __shared__ float hL[64 * 36];
  __shared__ float mxL[64 * 40];
  const int tid = threadIdx.x;
  const int r0 = blockIdx.x * 64;                    // 640 blocks x 64 rows
  for (int i = tid; i < 120 * 35; i += 256) { int j = i / 35, d = i - j * 35; dwL[j * 36 + d] = dw[i]; }
  for (int i = tid; i < 35 * 35; i += 256)  { int j = i / 35, d = i - j * 35; owL[j * 36 + d] = ow[i]; }
  for (int i = tid; i < 64 * 40; i += 256)  mxL[i] = maxc[(size_t)r0 * 40 + i];
  __syncthreads();
  for (int t = tid; t < 64 * 35; t += 256) {
    const int row = t / 35, d = t - row * 35;
    const int rg = r0 + row;
    const int b = rg / NBLK;
    const int p0 = pos[b * 2], p1 = pos[b * 2 + 1];
    int e1 = min(p0, p1), e2 = max(p0, p1);
    if (e1 == 0) { e1 = 1; e2 += 1; }
    float a = db[d];
#pragma unroll
    for (int s = 0; s < SEQ; ++s) {
      const int k = (s >= e1) + (s >= e2);           // region of position s
      a += mxL[row * 40 + s] * dwL[(k * SEQ + s) * 36 + d];
    }
    hL[row * 36 + d] = a;
  }
  __syncthreads();
  for (int t = tid; t < 64 * 35; t += 256) {
    const int row = t / 35, c = t - row * 35;
    float a = ob[c];
#pragma unroll
    for (int d = 0; d < DH; ++d) a += hL[row * 36 + d] * owL[d * 36 + c];
    out[(size_t)(r0 + row) * NCLS + c] = a;
  }
}

extern "C" void kernel_launch(void* const* d_in, const int* in_sizes, int n_in,
                              void* d_out, int out_size, void* d_ws, size_t ws_size,
                              hipStream_t stream) {
  const int*   x     = (const int*)d_in[0];
  const int*   pos   = (const int*)d_in[1];
  const float* w2v   = (const float*)d_in[2];
  const float* convw = (const float*)d_in[3];
  const float* convb = (const float*)d_in[4];
  const float* dw    = (const float*)d_in[5];
  const float* db    = (const float*)d_in[6];
  const float* ow    = (const float*)d_in[7];
  const float* ob    = (const float*)d_in[8];
  float* out = (float*)d_out;

  char* ws = (char*)d_ws;
  u16* embp = (u16*)ws;                                   // 8192*42*320*2 = 220,200,960 B
  u16* Bt   = (u16*)(ws + 220200960);                     // 192*960*2    =     368,640 B
  float* maxc = (float*)(ws + 220200960 + 368640);        // 40960*40*4   =   6,553,600 B

  k_gather<<<53760, 256, 0, stream>>>(x, w2v, embp);      // 8192*42*40/256
  k_prepB<<<720, 256, 0, stream>>>(convw, Bt);            // 192*960/256
  k_conv_gemm<<<2560, 512, 0, stream>>>(embp, Bt, convb, maxc);  // 327680/128
  k_dense<<<640, 256, 0, stream>>>(maxc, pos, dw, db, ow, ob, out);
}

// Round 3
// 372.230 us; speedup vs baseline: 4.3039x; 1.0541x over previous
//
#include <hip/hip_runtime.h>

typedef short bf16x8 __attribute__((ext_vector_type(8)));
typedef float f32x4 __attribute__((ext_vector_type(4)));
typedef unsigned short u16;
typedef u16 ushort8v __attribute__((ext_vector_type(8)));

// ---- constants ----
#define VOCAB 100000
#define EMB 300
#define SEQ 40
#define BATCH 8192
#define COUT 210
#define NBLK 5
#define KPOOL 38
#define DH 35
#define NCLS 35
#define PADROWS 42          // 1 zero row + 40 seq + 1 zero row
#define PCOL 320            // padded emb row (3*320 = 960 = 30*32)
#define KDIM 960
#define NUSE 192            // only channels 0..189 feed the pool; compute 12 n-tiles
#define BM 128
#define BK 64
#define KSTEPS 15           // 960/64
#define ABYTES 16384        // 128*64*2
#define BBYTES 24576        // 192*64*2

__device__ __forceinline__ u16 f2bf(float f) {
  unsigned u = __float_as_uint(f);
  unsigned r = 0x7FFFu + ((u >> 16) & 1u);
  return (u16)((u + r) >> 16);
}

__device__ __forceinline__ void gload_lds16(void* lds, const void* g) {
  __builtin_amdgcn_global_load_lds(
      (const __attribute__((address_space(1))) void*)g,
      (__attribute__((address_space(3))) void*)lds, 16, 0, 0);
}

// ---- kernel 1: embedding gather -> padded bf16 [BATCH][42][320] ----
__global__ __launch_bounds__(256) void k_gather(const int* __restrict__ x,
                                                const float* __restrict__ w2v,
                                                u16* __restrict__ embp) {
  int g = blockIdx.x * 256 + threadIdx.x;      // 8192*42*40 chunks of 8 bf16
  int r = g / 40, ck = g - r * 40;
  int b = r / PADROWS, sp = r - b * PADROWS;
  float v[8] = {0.f, 0.f, 0.f, 0.f, 0.f, 0.f, 0.f, 0.f};
  if (sp >= 1 && sp <= SEQ && ck <= 37) {
    int idx = x[b * SEQ + sp - 1];
    const float* src = w2v + (size_t)idx * EMB + ck * 8;
    float4 f0 = *(const float4*)src;           // w2v rows are 1200B -> 16B aligned
    v[0] = f0.x; v[1] = f0.y; v[2] = f0.z; v[3] = f0.w;
    if (ck < 37) {
      float4 f1 = *(const float4*)(src + 4);
      v[4] = f1.x; v[5] = f1.y; v[6] = f1.z; v[7] = f1.w;
    }
  }
  ushort8v o;
#pragma unroll
  for (int j = 0; j < 8; ++j) o[j] = f2bf(v[j]);
  *(ushort8v*)(embp + (size_t)g * 8) = o;
}

// ---- kernel 2: conv_w [3][300][210] -> Bt bf16 [192 cols][960 k] (zero padded) ----
__global__ __launch_bounds__(256) void k_prepB(const float* __restrict__ convw,
                                               u16* __restrict__ Bt) {
  int id = blockIdx.x * 256 + threadIdx.x;     // 192*960 = 184320
  if (id >= NUSE * KDIM) return;
  int col = id / KDIM, k = id - col * KDIM;
  int kh = k / PCOL, e = k - kh * PCOL;
  float v = (e < EMB) ? convw[(kh * EMB + e) * COUT + col] : 0.f;
  Bt[id] = f2bf(v);
}

// ---- kernel 3: conv GEMM (M=327680, N=192, K=960) + bias + relu + channel-group max ----
// 512 threads = 8 waves as 2(M) x 4(N); wave tile 64x48 (4x3 frags of 16x16).
// BK=64, double-buffered LDS (2x40KB), prefetch-ahead pipeline with ONE barrier/K-step:
//   STAGE(next) ; ds_read+MFMA(cur) ; __syncthreads (drains vmcnt -> next ready, cur reads done)
// Each thread issues exactly 5 global_load_lds (2 A + 3 B) per K-step.
__global__ __launch_bounds__(512) void k_conv_gemm(const u16* __restrict__ embp,
                                                   const u16* __restrict__ Bt,
                                                   const float* __restrict__ convb,
                                                   float* __restrict__ maxc) {
  __shared__ __align__(16) char smem[2 * (ABYTES + BBYTES)];   // 81920 B
  float* act = (float*)smem;   // [32][194] f32 (epilogue reuse, 24832 B)

  const int tid = threadIdx.x;
  const int lane = tid & 63;
  const int w = tid >> 6;
  const int wr = w >> 2, wc = w & 3;
  const int l15 = lane & 15, l4 = lane >> 4;
  const int m0 = blockIdx.x * BM;

  // A staging: chunk c in [0,1024): granule g=c>>7 (k = g*8), row r=c&127. Thread owns c=tid, tid+512.
  // LDS linear at c*16 => wave-uniform base + lane*16 (consecutive tids -> consecutive chunks).
  const int ar0 = tid & 127, ag0 = tid >> 7;
  const int am0 = m0 + ar0;
  const int ab0 = am0 / SEQ, as0 = am0 - ab0 * SEQ;
  const u16* gA0 = embp + (size_t)(ab0 * PADROWS + as0) * PCOL + ag0 * 8;
  const int c1 = tid + 512;
  const int ar1 = c1 & 127, ag1 = c1 >> 7;
  const int am1 = m0 + ar1;
  const int ab1 = am1 / SEQ, as1 = am1 - ab1 * SEQ;
  const u16* gA1 = embp + (size_t)(ab1 * PADROWS + as1) * PCOL + ag1 * 8;
  // B staging: chunk c in [0,1536): g=c/192 (k=g*8), col=c%192. Thread owns c=tid, tid+512, tid+1024.
  const int bg0 = tid / NUSE, bc0 = tid - bg0 * NUSE;
  const u16* gB0 = Bt + bc0 * KDIM + bg0 * 8;
  const int cb1 = tid + 512;
  const int bg1 = cb1 / NUSE, bc1 = cb1 - bg1 * NUSE;
  const u16* gB1 = Bt + bc1 * KDIM + bg1 * 8;
  const int cb2 = tid + 1024;
  const int bg2 = cb2 / NUSE, bc2 = cb2 - bg2 * NUSE;
  const u16* gB2 = Bt + bc2 * KDIM + bg2 * 8;

  f32x4 acc[4][3];
  const f32x4 zero = {0.f, 0.f, 0.f, 0.f};
#pragma unroll
  for (int i = 0; i < 4; ++i)
#pragma unroll
    for (int j = 0; j < 3; ++j) acc[i][j] = zero;

#define STAGE(buf, kofs)                                                    \
  {                                                                         \
    char* A_ = smem + (buf) * ABYTES;                                       \
    char* B_ = smem + 2 * ABYTES + (buf) * BBYTES;                          \
    gload_lds16(A_ + tid * 16, gA0 + (kofs));                               \
    gload_lds16(A_ + (tid + 512) * 16, gA1 + (kofs));                       \
    gload_lds16(B_ + tid * 16, gB0 + (kofs));                               \
    gload_lds16(B_ + (tid + 512) * 16, gB1 + (kofs));                       \
    gload_lds16(B_ + (tid + 1024) * 16, gB2 + (kofs));                      \
  }

  STAGE(0, 0);
  __syncthreads();

  int cur = 0;
#pragma unroll 1
  for (int kt = 0; kt < KSTEPS; ++kt) {
    if (kt + 1 < KSTEPS) STAGE(cur ^ 1, (kt + 1) * BK);
    const char* A_ = smem + cur * ABYTES;
    const char* B_ = smem + 2 * ABYTES + cur * BBYTES;
#pragma unroll
    for (int kk = 0; kk < 2; ++kk) {
      bf16x8 a[4], b[3];
#pragma unroll
      for (int fm = 0; fm < 4; ++fm)
        a[fm] = *(const bf16x8*)(A_ + ((kk * 4 + l4) * 128 + wr * 64 + fm * 16 + l15) * 16);
#pragma unroll
      for (int fn = 0; fn < 3; ++fn)
        b[fn] = *(const bf16x8*)(B_ + ((kk * 4 + l4) * 192 + wc * 48 + fn * 16 + l15) * 16);
#pragma unroll
      for (int fm = 0; fm < 4; ++fm)
#pragma unroll
        for (int fn = 0; fn < 3; ++fn)
          acc[fm][fn] = __builtin_amdgcn_mfma_f32_16x16x32_bf16(a[fm], b[fn], acc[fm][fn], 0, 0, 0);
    }
    __syncthreads();
    cur ^= 1;
  }
#undef STAGE

  // epilogue: 4 chunks of 32 rows; bias+relu -> LDS -> per-(row,group) max over 38 channels.
  // Fully unrolled: every acc[] index compile-time (rule #20).
#pragma unroll
  for (int ch = 0; ch < 4; ++ch) {
    if (wr == (ch >> 1)) {
      const int fbase = (ch & 1) * 2;
#pragma unroll
      for (int fi = 0; fi < 2; ++fi) {
#pragma unroll
        for (int fn = 0; fn < 3; ++fn) {
          const int col = wc * 48 + fn * 16 + l15;   // < 192 < 210
          const float bias = convb[col];
#pragma unroll
          for (int rg = 0; rg < 4; ++rg) {
            const int rloc = fi * 16 + l4 * 4 + rg;  // 0..31 within chunk
            float vv = acc[fbase + fi][fn][rg] + bias;
            act[rloc * 194 + col] = fmaxf(vv, 0.f);
          }
        }
      }
    }
    __syncthreads();
    if (tid < 160) {                                  // 32 rows x 5 groups
      const int rl = tid / 5, gq = tid - rl * 5;
      const float* ap = act + rl * 194 + gq * KPOOL;
      float mx = 0.f;                                 // relu => values >= 0
#pragma unroll
      for (int i = 0; i < KPOOL; ++i) mx = fmaxf(mx, ap[i]);
      const int m = m0 + ch * 32 + rl;
      const int bb = m / SEQ, ss = m - bb * SEQ;
      maxc[(bb * NBLK + gq) * SEQ + ss] = mx;         // unmasked max; mask applied in k_dense
    }
    __syncthreads();
  }
}

// ---- kernel 4: region-masked dense (120->35) + out (35->35) ----
__global__ __launch_bounds__(256) void k_dense(const float* __restrict__ maxc,
                                               const int* __restrict__ pos,
                                               const float* __restrict__ dw,
                                               const float* __restrict__ db,
                                               const float* __restrict__ ow,
                                               const float* __restrict__ ob,
                                               float* __restrict__ out) {
  __shared__ float dwL[120 * 36];
  __shared__ float owL[35 * 36];
  __shared__ float hL[64 * 36];
  __shared__ float mxL[64 * 40];
  const int tid = threadIdx.x;
  const int r0 = blockIdx.x * 64;                    // 640 blocks x 64 rows
  for (int i = tid; i < 120 * 35; i += 256) { int j = i / 35, d = i - j * 35; dwL[j * 36 + d] = dw[i]; }
  for (int i = tid; i < 35 * 35; i += 256)  { int j = i / 35, d = i - j * 35; owL[j * 36 + d] = ow[i]; }
  for (int i = tid; i < 64 * 40; i += 256)  mxL[i] = maxc[(size_t)r0 * 40 + i];
  __syncthreads();
  for (int t = tid; t < 64 * 35; t += 256) {
    const int row = t / 35, d = t - row * 35;
    const int rg = r0 + row;
    const int b = rg / NBLK;
    const int p0 = pos[b * 2], p1 = pos[b * 2 + 1];
    int e1 = min(p0, p1), e2 = max(p0, p1);
    if (e1 == 0) { e1 = 1; e2 += 1; }
    float a = db[d];
#pragma unroll
    for (int s = 0; s < SEQ; ++s) {
      const int k = (s >= e1) + (s >= e2);           // region of position s
      a += mxL[row * 40 + s] * dwL[(k * SEQ + s) * 36 + d];
    }
    hL[row * 36 + d] = a;
  }
  __syncthreads();
  for (int t = tid; t < 64 * 35; t += 256) {
    const int row = t / 35, c = t - row * 35;
    float a = ob[c];
#pragma unroll
    for (int d = 0; d < DH; ++d) a += hL[row * 36 + d] * owL[d * 36 + c];
    out[(size_t)(r0 + row) * NCLS + c] = a;
  }
}

extern "C" void kernel_launch(void* const* d_in, const int* in_sizes, int n_in,
                              void* d_out, int out_size, void* d_ws, size_t ws_size,
                              hipStream_t stream) {
  const int*   x     = (const int*)d_in[0];
  const int*   pos   = (const int*)d_in[1];
  const float* w2v   = (const float*)d_in[2];
  const float* convw = (const float*)d_in[3];
  const float* convb = (const float*)d_in[4];
  const float* dw    = (const float*)d_in[5];
  const float* db    = (const float*)d_in[6];
  const float* ow    = (const float*)d_in[7];
  const float* ob    = (const float*)d_in[8];
  float* out = (float*)d_out;

  char* ws = (char*)d_ws;
  u16* embp = (u16*)ws;                                   // 8192*42*320*2 = 220,200,960 B
  u16* Bt   = (u16*)(ws + 220200960);                     // 192*960*2    =     368,640 B
  float* maxc = (float*)(ws + 220200960 + 368640);        // 40960*40*4   =   6,553,600 B

  k_gather<<<53760, 256, 0, stream>>>(x, w2v, embp);      // 8192*42*40/256
  k_prepB<<<720, 256, 0, stream>>>(convw, Bt);            // 192*960/256
  k_conv_gemm<<<2560, 512, 0, stream>>>(embp, Bt, convb, maxc);  // 327680/128
  k_dense<<<640, 256, 0, stream>>>(maxc, pos, dw, db, ow, ob, out);
}